// Round 3
// baseline (116.074 us; speedup 1.0000x reference)
//
#include <hip/hip_runtime.h>

// GHM loss: focal (ch 0) + GHMR (ch 1..7), 3 scalar outputs.
//
// Pass 1 (streaming, grid-stride by WAVE):
//   A wave processes 64 consecutive pixels = 128 consecutive float4s.
//   Lane i loads f4[base+i] and f4[base+64+i]  -> UNIT-STRIDE, 16B/lane
//   (the previous kernel's stride-32B pattern doubled L1 transactions and
//    capped delivered BW at ~10 B/cyc/CU).
//   Even lane i holds ch0-3 halves of pixels p1=base_px+i/2, p2=base_px+32+i/2;
//   odd lanes hold ch4-7 halves of the same pixels. `valid` is computed on
//   even lanes and distributed to the odd partner via one __shfl.
//   Uniform 8-slot GHMR bin pipeline; the 2 cls slots on even lanes are
//   masked out (d2m=-1 fails every predicate, C[0]=-0.5).
//   Bin test algebraic: g*10 >= b  <=>  d^2 >= C_b = b^2*mu^2/(100-b^2).
//   Counts via ballot -> popcountll (wave-uniform -> scalar pipe).
// Per-block partials in d_ws (deterministic, no atomics).
// Pass 2: 1 block reduces partials and computes the 3 outputs.
//
// Partials layout [quantity][block], NQ = 22:
//   q 0..9  : cumulative loss sums  l_b  (loss where g*10 >= b, valid)
//   q 10    : focal sum
//   q 11    : valid pixel count
//   q 12..21: cumulative counts     c_b

#define NQ 22

__global__ __launch_bounds__(256)
void ghm_pass1(const float4* __restrict__ preds, const float4* __restrict__ tgts,
               int n_pix, float* __restrict__ part, int nb) {
    constexpr float MU2 = 4.0e-4f;
    const float C[10] = { -0.5f,
                          4.0404041e-6f, 1.6666667e-5f, 3.9560441e-5f,
                          7.6190476e-5f, 1.3333333e-4f, 2.2500000e-4f,
                          3.8431373e-4f, 7.1111111e-4f, 1.7052632e-3f };

    float lac[10];
#pragma unroll
    for (int b = 0; b < 10; ++b) lac[b] = 0.f;
    float facc = 0.f;
    unsigned int cnt[10] = {0,0,0,0,0,0,0,0,0,0};
    unsigned int vcnt = 0;

    const int tid  = threadIdx.x;
    const int lane = tid & 63;
    const int wid  = (blockIdx.x * 256 + tid) >> 6;   // global wave id
    const int nwav = (gridDim.x * 256) >> 6;
    const int nch  = n_pix >> 6;                      // 64-pixel chunks
    const bool evenlane = (lane & 1) == 0;

    for (int ch = wid; ch < nch; ch += nwav) {
        const size_t b4 = (size_t)ch * 128;
        float4 pA = preds[b4 + lane];
        float4 pB = preds[b4 + 64 + lane];
        float4 tA = tgts [b4 + lane];
        float4 tB = tgts [b4 + 64 + lane];

        // cls targets live in .x of even lanes' A/B
        bool v1e = tA.x > 0.1f;
        bool v2e = tB.x > 0.1f;

        if (evenlane) {
            // focal for the two pixels this lane owns the cls half of
            float x1 = pA.x;
            float xt1 = v1e ? x1 : 1.f - x1;
            float at1 = v1e ? 0.25f : 0.75f;
            float om1 = 1.f - xt1;
            facc += -at1 * om1 * om1 * __logf(xt1 + 1e-5f);
            float x2 = pB.x;
            float xt2 = v2e ? x2 : 1.f - x2;
            float at2 = v2e ? 0.25f : 0.75f;
            float om2 = 1.f - xt2;
            facc += -at2 * om2 * om2 * __logf(xt2 + 1e-5f);
        }
        vcnt += (unsigned)__builtin_popcountll(__ballot(evenlane && v1e));
        vcnt += (unsigned)__builtin_popcountll(__ballot(evenlane && v2e));

        // distribute valid bits to the odd partner lane
        float pk = (v1e ? 1.f : 0.f) + (v2e ? 2.f : 0.f);
        pk = __shfl(pk, lane & ~1);
        int pki = (int)pk;
        bool v1 = (pki & 1) != 0;
        bool v2 = (pki & 2) != 0;

        float pd[8] = {pA.x, pA.y, pA.z, pA.w, pB.x, pB.y, pB.z, pB.w};
        float td[8] = {tA.x, tA.y, tA.z, tA.w, tB.x, tB.y, tB.z, tB.w};
        bool  m[8];
        m[0] = v1 && !evenlane;  m[1] = v1;  m[2] = v1;  m[3] = v1;
        m[4] = v2 && !evenlane;  m[5] = v2;  m[6] = v2;  m[7] = v2;

#pragma unroll
        for (int e = 0; e < 8; ++e) {
            float d  = pd[e] - td[e];
            float d2 = d * d;
            float s  = __builtin_amdgcn_sqrtf(__builtin_fmaf(d, d, MU2));
            float loss = s - 0.02f;
            float d2m = m[e] ? d2 : -1.f;
#pragma unroll
            for (int b = 0; b < 10; ++b) {
                bool pb = d2m >= C[b];
                lac[b] += pb ? loss : 0.f;
                cnt[b] += (unsigned)__builtin_popcountll(__ballot(pb));
            }
        }
    }

    // generic remainder (n_pix % 64) — not taken for this shape
    for (int i = (nch << 6) + wid * 64 + lane; i < n_pix; i += nwav * 64) {
        const size_t base = 2 * (size_t)i;
        float4 p0 = preds[base], p1 = preds[base + 1];
        float4 t0 = tgts[base],  t1 = tgts[base + 1];
        float x = p0.x, y = t0.x;
        bool valid = y > 0.1f;
        float x_t = valid ? x : 1.f - x;
        float a_t = valid ? 0.25f : 0.75f;
        float om = 1.f - x_t;
        facc += -a_t * om * om * __logf(x_t + 1e-5f);
        vcnt += valid ? 1u : 0u;
        float pd[7] = {p0.y, p0.z, p0.w, p1.x, p1.y, p1.z, p1.w};
        float td[7] = {t0.y, t0.z, t0.w, t1.x, t1.y, t1.z, t1.w};
#pragma unroll
        for (int c = 0; c < 7; ++c) {
            float d = pd[c] - td[c];
            float d2 = d * d;
            float s = __builtin_amdgcn_sqrtf(__builtin_fmaf(d, d, MU2));
            float loss = s - 0.02f;
            float d2m = valid ? d2 : -1.f;
#pragma unroll
            for (int b = 0; b < 10; ++b) {
                bool pb = d2m >= C[b];
                lac[b] += pb ? loss : 0.f;
                cnt[b] += pb ? 1u : 0u;
            }
        }
    }

    // wave shuffle reduction of the 11 float accumulators
    float vq[11] = { lac[0], lac[1], lac[2], lac[3], lac[4],
                     lac[5], lac[6], lac[7], lac[8], lac[9], facc };
#pragma unroll
    for (int q = 0; q < 11; ++q) {
        float v = vq[q];
        v += __shfl_down(v, 32);
        v += __shfl_down(v, 16);
        v += __shfl_down(v, 8);
        v += __shfl_down(v, 4);
        v += __shfl_down(v, 2);
        v += __shfl_down(v, 1);
        vq[q] = v;
    }
    // counts: uniform per wave already (ballot path); remainder path made
    // them per-lane, so reduce them too (cheap, correct in both cases)
    unsigned cq[11];
#pragma unroll
    for (int b = 0; b < 10; ++b) cq[b] = cnt[b];
    cq[10] = vcnt;
#pragma unroll
    for (int q = 0; q < 11; ++q) {
        unsigned v = cq[q];
        v += __shfl_down(v, 32);
        v += __shfl_down(v, 16);
        v += __shfl_down(v, 8);
        v += __shfl_down(v, 4);
        v += __shfl_down(v, 2);
        v += __shfl_down(v, 1);
        cq[q] = v;
    }

    __shared__ float sm[4][NQ];
    const int wave = tid >> 6;
    if (lane == 0) {
#pragma unroll
        for (int q = 0; q < 11; ++q) sm[wave][q] = vq[q];
        sm[wave][11] = (float)((double)cq[10] / 64.0 + 0.5 >= 0 ? cq[10] : cq[10]); // vcnt (ballot path counted once per wave via uniform adds across 64 lanes -> reduced => x64? no: uniform value added identically per lane, shuffle-sum multiplies by 64)
#pragma unroll
        for (int b = 0; b < 10; ++b) sm[wave][12 + b] = (float)cq[b];
    }
    __syncthreads();
    if (tid < NQ) {
        float v = sm[0][tid] + sm[1][tid] + sm[2][tid] + sm[3][tid];
        // ballot-path counts are wave-uniform; the shuffle-sum above scaled
        // them by 64. Undo that here (remainder path contributes per-lane
        // counts, which are exact under the same scaling only when n_pix%64
        // == 0; for this problem n_pix % 64 == 0 and remainder is empty).
        if (tid >= 11) v *= (1.f / 64.f);
        part[(size_t)tid * nb + blockIdx.x] = v;
    }
}

__global__ __launch_bounds__(256)
void ghm_final(const float* __restrict__ part, int nb,
               float* __restrict__ out, float inv_npix) {
    __shared__ float red[NQ];
    const int tid = threadIdx.x;
    const int wave = tid >> 6, lane = tid & 63;

    for (int q = wave; q < NQ; q += 4) {
        float v = 0.f;
        for (int i = lane; i < nb; i += 64) v += part[(size_t)q * nb + i];
        v += __shfl_down(v, 32);
        v += __shfl_down(v, 16);
        v += __shfl_down(v, 8);
        v += __shfl_down(v, 4);
        v += __shfl_down(v, 2);
        v += __shfl_down(v, 1);
        if (lane == 0) red[q] = v;
    }
    __syncthreads();

    if (tid == 0) {
        float tot = fmaxf(red[11], 1.f);
        float n = 0.f, sum = 0.f;
#pragma unroll
        for (int b = 0; b < 10; ++b) {
            float cb = red[12 + b] - (b < 9 ? red[12 + b + 1] : 0.f);
            float lb = red[b]      - (b < 9 ? red[b + 1]      : 0.f);
            if (cb > 0.f) {
                n += 1.f;
                sum += tot / fmaxf(0.3f * cb, 1e-30f) * lb;
            }
        }
        float reg = sum / fmaxf(n, 1.f) / tot;
        float cls = red[10] * inv_npix;
        out[0] = cls + reg;
        out[1] = reg;
        out[2] = cls;
    }
}

extern "C" void kernel_launch(void* const* d_in, const int* in_sizes, int n_in,
                              void* d_out, int out_size, void* d_ws, size_t ws_size,
                              hipStream_t stream) {
    const float* preds = (const float*)d_in[0];
    const float* tgts  = (const float*)d_in[1];
    const int n_pix = in_sizes[0] / 8;

    size_t nb_max = ws_size / (NQ * sizeof(float));
    int nb = (int)(nb_max < 2048 ? nb_max : 2048);
    if (nb < 1) nb = 1;

    float* part = (float*)d_ws;
    ghm_pass1<<<nb, 256, 0, stream>>>((const float4*)preds, (const float4*)tgts,
                                      n_pix, part, nb);
    ghm_final<<<1, 256, 0, stream>>>(part, nb, (float*)d_out,
                                     1.f / (float)n_pix);
}

// Round 4
// 70.661 us; speedup vs baseline: 1.6427x; 1.6427x over previous
//
#include <hip/hip_runtime.h>

// GHM loss: focal (ch 0) + GHMR (ch 1..7), 3 scalar outputs.
//
// Pass 1: ONE-SHOT grid (no grid-stride convoy): thread g handles pixels
//   2g, 2g+1 via 8 independent dwordx4 loads issued at wave start. A wave
//   never parks on vmcnt between iterations (there are none), so the
//   memory system sees a continuous stream of fresh waves' loads instead
//   of synchronized 4KB-burst convoys (~31K-cycle effective latency seen
//   in rounds 1-3, all pinned at 112us regardless of VALU/coalescing).
//   Bin test algebraic: g*10 >= b  <=>  d^2 >= C_b = b^2*mu^2/(100-b^2).
//   Counts: ballot -> popcll (wave-uniform, scalar pipe). Loss sums:
//   cndmask+add reusing the same compare.
// Pass 2: 22 blocks, block q reduces part[q][0..nb) -> red[q].
// Pass 3: 1 tiny block computes the 3 outputs from red[22].
//
// Partials layout [quantity][block], NQ = 22:
//   q 0..9  : cumulative loss sums  l_b  (loss where g*10 >= b, valid)
//   q 10    : focal sum
//   q 11    : valid pixel count
//   q 12..21: cumulative counts     c_b

#define NQ 22

__device__ __forceinline__ float wave_sum(float v) {
    v += __shfl_down(v, 32);
    v += __shfl_down(v, 16);
    v += __shfl_down(v, 8);
    v += __shfl_down(v, 4);
    v += __shfl_down(v, 2);
    v += __shfl_down(v, 1);
    return v;
}

__global__ __launch_bounds__(256)
void ghm_pass1(const float4* __restrict__ preds, const float4* __restrict__ tgts,
               int n_pix, float* __restrict__ part, int nb) {
    constexpr float MU2 = 4.0e-4f;
    const float C[10] = { -0.5f,
                          4.0404041e-6f, 1.6666667e-5f, 3.9560441e-5f,
                          7.6190476e-5f, 1.3333333e-4f, 2.2500000e-4f,
                          3.8431373e-4f, 7.1111111e-4f, 1.7052632e-3f };

    float lac[10];
#pragma unroll
    for (int b = 0; b < 10; ++b) lac[b] = 0.f;
    float facc = 0.f;
    unsigned int cnt[10] = {0,0,0,0,0,0,0,0,0,0};
    unsigned int vcnt = 0;

    const int tid = threadIdx.x;
    const long total4 = 2L * (long)n_pix;   // float4 count per array

    // one iteration for the launched grid; loop kept only for ws-size fallback
    for (long g = (long)blockIdx.x * 256 + tid; 2 * g < (long)n_pix;
         g += (long)gridDim.x * 256) {
        const long b4 = 4 * g;
        const bool in1 = (2 * g + 1) < (long)n_pix;
        const long i1 = (b4 + 1 < total4) ? b4 + 1 : total4 - 1;
        const long i2 = (b4 + 2 < total4) ? b4 + 2 : total4 - 1;
        const long i3 = (b4 + 3 < total4) ? b4 + 3 : total4 - 1;

        float4 pA = preds[b4], pB = preds[i1], pC = preds[i2], pD = preds[i3];
        float4 tA = tgts[b4],  tB = tgts[i1],  tC = tgts[i2],  tD = tgts[i3];

        bool v1 = tA.x > 0.1f;            // pixel 2g (in-bounds by loop cond)
        bool v2 = in1 && (tC.x > 0.1f);   // pixel 2g+1

        // focal, pixel 2g
        {
            float x  = pA.x;
            float xt = v1 ? x : 1.f - x;
            float at = v1 ? 0.25f : 0.75f;
            float om = 1.f - xt;
            facc += -at * om * om * __logf(xt + 1e-5f);
        }
        // focal, pixel 2g+1 (masked if out of bounds)
        {
            bool vv  = tC.x > 0.1f;
            float x  = pC.x;
            float xt = vv ? x : 1.f - x;
            float at = vv ? 0.25f : 0.75f;
            float om = 1.f - xt;
            float f  = -at * om * om * __logf(xt + 1e-5f);
            facc += in1 ? f : 0.f;
        }
        vcnt += (unsigned)__builtin_popcountll(__ballot(v1));
        vcnt += (unsigned)__builtin_popcountll(__ballot(v2));

        float pd[14] = {pA.y,pA.z,pA.w, pB.x,pB.y,pB.z,pB.w,
                        pC.y,pC.z,pC.w, pD.x,pD.y,pD.z,pD.w};
        float td[14] = {tA.y,tA.z,tA.w, tB.x,tB.y,tB.z,tB.w,
                        tC.y,tC.z,tC.w, tD.x,tD.y,tD.z,tD.w};
#pragma unroll
        for (int e = 0; e < 14; ++e) {
            bool m   = (e < 7) ? v1 : v2;
            float d  = pd[e] - td[e];
            float d2 = d * d;
            float s  = __builtin_amdgcn_sqrtf(__builtin_fmaf(d, d, MU2));
            float loss = s - 0.02f;
            float d2m = m ? d2 : -1.f;
#pragma unroll
            for (int b = 0; b < 10; ++b) {
                bool pb = d2m >= C[b];
                lac[b] += pb ? loss : 0.f;
                cnt[b] += (unsigned)__builtin_popcountll(__ballot(pb));
            }
        }
    }

    // reduce: floats via shuffles; counts are already wave-uniform
    float vq[11] = { lac[0], lac[1], lac[2], lac[3], lac[4],
                     lac[5], lac[6], lac[7], lac[8], lac[9], facc };
#pragma unroll
    for (int q = 0; q < 11; ++q) vq[q] = wave_sum(vq[q]);

    __shared__ float sm[4][NQ];
    const int wave = tid >> 6, lane = tid & 63;
    if (lane == 0) {
#pragma unroll
        for (int q = 0; q < 11; ++q) sm[wave][q] = vq[q];
        sm[wave][11] = (float)vcnt;
#pragma unroll
        for (int b = 0; b < 10; ++b) sm[wave][12 + b] = (float)cnt[b];
    }
    __syncthreads();
    if (tid < NQ) {
        float v = sm[0][tid] + sm[1][tid] + sm[2][tid] + sm[3][tid];
        part[(size_t)tid * nb + blockIdx.x] = v;
    }
}

__global__ __launch_bounds__(256)
void ghm_pass2(const float* __restrict__ part, int nb, float* __restrict__ red) {
    const int q = blockIdx.x;
    const int tid = threadIdx.x;
    float v = 0.f;
    for (int i = tid; i < nb; i += 256) v += part[(size_t)q * nb + i];
    v = wave_sum(v);
    __shared__ float wv[4];
    if ((tid & 63) == 0) wv[tid >> 6] = v;
    __syncthreads();
    if (tid == 0) red[q] = wv[0] + wv[1] + wv[2] + wv[3];
}

__global__ __launch_bounds__(64)
void ghm_pass3(const float* __restrict__ red, float* __restrict__ out,
               float inv_npix) {
    if (threadIdx.x == 0) {
        float tot = fmaxf(red[11], 1.f);
        float n = 0.f, sum = 0.f;
#pragma unroll
        for (int b = 0; b < 10; ++b) {
            float cb = red[12 + b] - (b < 9 ? red[12 + b + 1] : 0.f);
            float lb = red[b]      - (b < 9 ? red[b + 1]      : 0.f);
            if (cb > 0.f) {
                n += 1.f;
                sum += tot / fmaxf(0.3f * cb, 1e-30f) * lb;
            }
        }
        float reg = sum / fmaxf(n, 1.f) / tot;
        float cls = red[10] * inv_npix;
        out[0] = cls + reg;
        out[1] = reg;
        out[2] = cls;
    }
}

extern "C" void kernel_launch(void* const* d_in, const int* in_sizes, int n_in,
                              void* d_out, int out_size, void* d_ws, size_t ws_size,
                              hipStream_t stream) {
    const float* preds = (const float*)d_in[0];
    const float* tgts  = (const float*)d_in[1];
    const int n_pix = in_sizes[0] / 8;

    long want_nb = ((long)n_pix + 511) / 512;          // one-shot: 2 px/thread
    long cap = ((long)(ws_size / sizeof(float)) - NQ) / NQ;
    long nb_l = want_nb < cap ? want_nb : cap;
    if (nb_l < 1) nb_l = 1;
    int nb = (int)nb_l;

    float* part = (float*)d_ws;
    float* red  = part + (size_t)NQ * nb;
    ghm_pass1<<<nb, 256, 0, stream>>>((const float4*)preds, (const float4*)tgts,
                                      n_pix, part, nb);
    ghm_pass2<<<NQ, 256, 0, stream>>>(part, nb, red);
    ghm_pass3<<<1, 64, 0, stream>>>(red, (float*)d_out, 1.f / (float)n_pix);
}